// Round 11
// baseline (245.857 us; speedup 1.0000x reference)
//
#include <hip/hip_runtime.h>
#include <math.h>

#define HW_     (1024 * 1024)
#define NPIX    (4 * HW_)               // 4,194,304 pixels
#define NG      (NPIX / 4)              // 1,048,576 float4 groups
#define NSETS   64
#define ACC_STRIDE 32                   // doubles/set: 0..7 sx, 8..15 sy, 16..23 cnt, 24 spw, 25 sxx
#define BLOCK_  256
#define TILE_G  512                     // groups per block tile (8 KB/plane/block)
#define RUN     2                       // consecutive 1KB wave-loads per plane
#define GRID1   (NG / TILE_G)           // 2048 blocks (= 8 per CU at VGPR<=64)

// Native clang vector type: __builtin_nontemporal_load requires a pointer to
// scalar/pointer/VECTOR type -- HIP_vector_type (float4) is rejected.
typedef float f32x4 __attribute__((ext_vector_type(4)));

// fast pow for x>0: v_log_f32 (log2) + v_mul + v_exp_f32 (exp2)
__device__ __forceinline__ float fast_pow_pos(float x, float p) {
    return __builtin_amdgcn_exp2f(p * __builtin_amdgcn_logf(x));
}

// Round 11: MORE CONCURRENCY IN THE STREAMING REGIME.
// R9/R10 established the real mechanism: MALL allocation churn governed the
// old 2.4 TB/s plateau; full-nt streaming reached ~3.4 TB/s (pass1 ~66us).
// In the new regime the limiter should be outstanding requests again --
// R6's "occupancy irrelevant" result was measured in the churn-limited
// regime and does not transfer. Two residues fixed: (1) grid 1024->2048
// (TILE_G 512, RUN 2): 8 blocks/CU, occupancy ~34%->~65%; (2) the R7
// sched_barriers (pinned plane order for a falsified DRAM-row theory) are
// deleted -- they capped per-wave MLP at RUN loads. nt loads throughout.
__global__ __launch_bounds__(BLOCK_, 4) void pass1_kernel(
    const float* __restrict__ x, const float* __restrict__ y,
    const float* __restrict__ mk, double* __restrict__ acc)
{
    const int tid  = threadIdx.x;
    const int wave = tid >> 6, lane = tid & 63;
    const int t    = blockIdx.x;            // 0..2047
    const int b    = t >> 9;                // 512 tiles per batch
    // float offset of this thread's r=0 chunk inside a plane:
    const size_t hw0 = (size_t)(t & 511) * (TILE_G * 4)
                     + (size_t)wave * (RUN * 256) + (size_t)lane * 4;

    const float* xp = x  + (size_t)(b * 3) * HW_ + hw0;
    const float* yp = y  + (size_t)(b * 3) * HW_ + hw0;
    const float* mp = mk + (size_t)(b * 8) * HW_ + hw0;

    // ---- x planes: plane-major, RUN x 1KB contiguous per wave per plane ----
    f32x4 xs[RUN], ys[RUN];
#pragma unroll
    for (int r = 0; r < RUN; ++r)
        xs[r] = __builtin_nontemporal_load((const f32x4*)(xp + r * 256));
#pragma unroll
    for (int c = 1; c < 3; ++c)
#pragma unroll
        for (int r = 0; r < RUN; ++r)
            xs[r] += __builtin_nontemporal_load(
                (const f32x4*)(xp + (size_t)c * HW_ + r * 256));
    // ---- y planes ----
#pragma unroll
    for (int r = 0; r < RUN; ++r)
        ys[r] = __builtin_nontemporal_load((const f32x4*)(yp + r * 256));
#pragma unroll
    for (int c = 1; c < 3; ++c)
#pragma unroll
        for (int r = 0; r < RUN; ++r)
            ys[r] += __builtin_nontemporal_load(
                (const f32x4*)(yp + (size_t)c * HW_ + r * 256));
    const float inv3 = 1.0f / 3.0f;
#pragma unroll
    for (int r = 0; r < RUN; ++r) { xs[r] *= inv3; ys[r] *= inv3; }

    // ---- mask planes: nt plane-major running argmax ----
    // strict >: first occurrence wins (jnp.argmax tie-break, c ascending)
    f32x4 best[RUN]; int4 bi[RUN];
#pragma unroll
    for (int r = 0; r < RUN; ++r) {
        best[r] = __builtin_nontemporal_load((const f32x4*)(mp + r * 256));
        bi[r].x = 0; bi[r].y = 0; bi[r].z = 0; bi[r].w = 0;
    }
#pragma unroll
    for (int c = 1; c < 8; ++c)
#pragma unroll
        for (int r = 0; r < RUN; ++r) {
            const f32x4 v = __builtin_nontemporal_load(
                (const f32x4*)(mp + (size_t)c * HW_ + r * 256));
            if (v.x > best[r].x) { best[r].x = v.x; bi[r].x = c; }
            if (v.y > best[r].y) { best[r].y = v.y; bi[r].y = c; }
            if (v.z > best[r].z) { best[r].z = v.z; bi[r].z = c; }
            if (v.w > best[r].w) { best[r].w = v.w; bi[r].w = c; }
        }

    // ---- accumulate RUN*4 pixels into the 26 per-thread accumulators ----
    float sx[8], sy[8], sc[8];
#pragma unroll
    for (int l = 0; l < 8; ++l) { sx[l] = 0.f; sy[l] = 0.f; sc[l] = 0.f; }
    float spw = 0.f, sxx = 0.f;

#define PIX(R, F)                                                           \
    {                                                                       \
        const float xav = xs[R].F;                                          \
        const float yav = ys[R].F;                                          \
        const int   lab = bi[R].F;                                          \
        _Pragma("unroll")                                                   \
        for (int l = 0; l < 8; ++l) {                                       \
            const bool p = (lab == l);                                      \
            sx[l] += p ? xav : 0.0f;                                        \
            sy[l] += p ? yav : 0.0f;                                        \
            sc[l] += p ? 1.0f : 0.0f;                                       \
        }                                                                   \
        spw += fast_pow_pos(xav, yav);  /* xav>0: mean of uniforms */       \
        sxx += xav * xav;                                                   \
    }

#pragma unroll
    for (int r = 0; r < RUN; ++r) { PIX(r, x) PIX(r, y) PIX(r, z) PIX(r, w) }
#undef PIX

    // ---- wave64 shuffle reduction of the 26 accumulators ----
#pragma unroll
    for (int off = 32; off > 0; off >>= 1) {
#pragma unroll
        for (int l = 0; l < 8; ++l) {
            sx[l] += __shfl_down(sx[l], off);
            sy[l] += __shfl_down(sy[l], off);
            sc[l] += __shfl_down(sc[l], off);
        }
        spw += __shfl_down(spw, off);
        sxx += __shfl_down(sxx, off);
    }
    __shared__ float red[4][26];
    if (lane == 0) {
#pragma unroll
        for (int l = 0; l < 8; ++l) {
            red[wave][l]      = sx[l];
            red[wave][8 + l]  = sy[l];
            red[wave][16 + l] = sc[l];
        }
        red[wave][24] = spw;
        red[wave][25] = sxx;
    }
    __syncthreads();
    if (tid < 26) {
        float s = red[0][tid] + red[1][tid] + red[2][tid] + red[3][tid];
        atomicAdd(&acc[(blockIdx.x & (NSETS - 1)) * ACC_STRIDE + tid],
                  (double)s);
    }
}

// ---- finalize: all three losses in f64, write 3 floats ----
__global__ void finalize_kernel(const double* __restrict__ acc,
                                float* __restrict__ out)
{
    __shared__ double sh[26];
    int t = threadIdx.x;
    if (t < 26) {
        double s = 0.0;
        for (int k = 0; k < NSETS; ++k) s += acc[k * ACC_STRIDE + t];
        sh[t] = s;
    }
    __syncthreads();
    if (t == 0) {
        const double invN = 1.0 / (double)NPIX;
        double l1 = sh[24];       // sum of pow over on-mask pixels
        double l3 = sh[25];       // sum of xa^2
        double l2 = 0.0;
        for (int l = 0; l < 8; ++l) {
            double SX  = sh[l];
            double XA  = SX * invN;
            double YA  = sh[8 + l] * invN;
            double cnt = sh[16 + l];
            double pw  = pow(XA, YA);
            l2 += pw;
            l1 += ((double)NPIX - cnt) * pw;          // off-mask pow terms
            l3 += cnt * XA * XA - 2.0 * XA * SX;      // per-label variance cross terms
        }
        out[0] = (float)(l1 * invN);
        out[1] = (float)l2;
        out[2] = (float)(l3 * invN);
    }
}

extern "C" void kernel_launch(void* const* d_in, const int* in_sizes, int n_in,
                              void* d_out, int out_size, void* d_ws, size_t ws_size,
                              hipStream_t stream)
{
    const float* x  = (const float*)d_in[0];
    const float* y  = (const float*)d_in[1];
    const float* mk = (const float*)d_in[2];
    float* out = (float*)d_out;

    double* acc = (double*)d_ws;                    // 64*32*8 = 16 KB
    (void)hipMemsetAsync(acc, 0, NSETS * ACC_STRIDE * 8, stream);

    pass1_kernel<<<GRID1, BLOCK_, 0, stream>>>(x, y, mk, acc);
    finalize_kernel<<<1, 64, 0, stream>>>(acc, out);
}